// Round 9
// baseline (551.030 us; speedup 1.0000x reference)
//
#include <hip/hip_runtime.h>
#include <hip/hip_cooperative_groups.h>
#include <math.h>

namespace cg = cooperative_groups;

#define N_NODES 50000
#define N_EDGES 800000
#define DIM 64
#define NPB 128
#define NPB_SHIFT 7
#define NBUCKET 391          // ceil(50000/128)
#define CAP 2560             // slot capacity per bucket (mean 2046, sd 45 -> 11 sigma)
#define EPB 2048             // edges per partition vblock
#define NBLK 391             // ceil(800000/2048)
#define NB_NL 782            // ceil(50000/64)
#define NB_GAT 3125          // 50000/16

// ---- bf16 helpers (RNE) ----
__device__ __forceinline__ ushort f2bf(float x) {
    unsigned b = __float_as_uint(x);
    return (ushort)((b + 0x7FFFu + ((b >> 16) & 1u)) >> 16);
}
__device__ __forceinline__ float bf2f(ushort u) {
    return __uint_as_float(((unsigned)u) << 16);
}

// ---- shared-memory union across phases (34 KB -> 4 blocks/CU) ----
struct SmemNL { ushort Ws[64][68]; ushort Us[64][68]; float hs[64][68]; };
struct SmemSort { int cnt[NPB]; int cur[NPB]; };
union Smem {
    SmemNL nl;
    int hist[NBUCKET];
    SmemSort srt;
};

// ============================== phase: node GEMM ==============================
// zb=bf16(h@W^T), zib=bf16(h@U^T), s_src/s_dst = attention projections of z.
template<bool IN_BF16>
__device__ __forceinline__ void nl_phase(
    int vb, const void* __restrict__ hin, const float* __restrict__ W,
    const float* __restrict__ U, const float* __restrict__ A,
    ushort* __restrict__ zb, ushort* __restrict__ zib,
    float* __restrict__ s_src, float* __restrict__ s_dst, Smem& sm)
{
    const int tid = threadIdx.x;
    const int row0 = vb * 64;

    for (int i = tid; i < 1024; i += 256) {
        int r = i >> 4, c = (i & 15) * 4;
        float4 w4 = ((const float4*)W)[i];
        float4 u4 = ((const float4*)U)[i];
        ushort4 wp, up;
        wp.x = f2bf(w4.x); wp.y = f2bf(w4.y); wp.z = f2bf(w4.z); wp.w = f2bf(w4.w);
        up.x = f2bf(u4.x); up.y = f2bf(u4.y); up.z = f2bf(u4.z); up.w = f2bf(u4.w);
        *(ushort4*)&sm.nl.Ws[r][c] = wp;
        *(ushort4*)&sm.nl.Us[r][c] = up;
        int n = row0 + r;
        float4 h4 = make_float4(0.f, 0.f, 0.f, 0.f);
        if (n < N_NODES) {
            if (IN_BF16) {
                ushort4 hb = ((const ushort4*)hin)[((size_t)n * DIM + c) >> 2];
                h4 = make_float4(bf2f(hb.x), bf2f(hb.y), bf2f(hb.z), bf2f(hb.w));
            } else {
                h4 = ((const float4*)hin)[((size_t)n * DIM + c) >> 2];
            }
        }
        *(float4*)&sm.nl.hs[r][c] = h4;
    }
    __syncthreads();

    const int rb = (tid >> 4) * 4;
    const int cb = (tid & 15) * 4;

    float accz[4][4] = {{0}}, accu[4][4] = {{0}};
    #pragma unroll 4
    for (int k = 0; k < DIM; k += 4) {
        float4 hv[4];
        float wv[4][4], uv[4][4];
        #pragma unroll
        for (int r = 0; r < 4; ++r) hv[r] = *(const float4*)&sm.nl.hs[rb + r][k];
        #pragma unroll
        for (int c = 0; c < 4; ++c) {
            ushort4 wb4 = *(const ushort4*)&sm.nl.Ws[cb + c][k];
            ushort4 ub4 = *(const ushort4*)&sm.nl.Us[cb + c][k];
            wv[c][0] = bf2f(wb4.x); wv[c][1] = bf2f(wb4.y); wv[c][2] = bf2f(wb4.z); wv[c][3] = bf2f(wb4.w);
            uv[c][0] = bf2f(ub4.x); uv[c][1] = bf2f(ub4.y); uv[c][2] = bf2f(ub4.z); uv[c][3] = bf2f(ub4.w);
        }
        #pragma unroll
        for (int r = 0; r < 4; ++r) {
            float h0 = hv[r].x, h1 = hv[r].y, h2 = hv[r].z, h3 = hv[r].w;
            #pragma unroll
            for (int c = 0; c < 4; ++c) {
                accz[r][c] += h0 * wv[c][0] + h1 * wv[c][1] + h2 * wv[c][2] + h3 * wv[c][3];
                accu[r][c] += h0 * uv[c][0] + h1 * uv[c][1] + h2 * uv[c][2] + h3 * uv[c][3];
            }
        }
    }

    float asrc[4], adst[4];
    #pragma unroll
    for (int c = 0; c < 4; ++c) { asrc[c] = A[cb + c]; adst[c] = A[DIM + cb + c]; }

    float ps[4], pd[4];
    #pragma unroll
    for (int r = 0; r < 4; ++r) {
        int n = row0 + rb + r;
        if (n < N_NODES) {
            ushort4 vz, vu;
            vz.x = f2bf(accz[r][0]); vz.y = f2bf(accz[r][1]);
            vz.z = f2bf(accz[r][2]); vz.w = f2bf(accz[r][3]);
            vu.x = f2bf(accu[r][0]); vu.y = f2bf(accu[r][1]);
            vu.z = f2bf(accu[r][2]); vu.w = f2bf(accu[r][3]);
            *(ushort4*)&zb[(size_t)n * DIM + cb]  = vz;
            *(ushort4*)&zib[(size_t)n * DIM + cb] = vu;
        }
        float s = 0.f, t = 0.f;
        #pragma unroll
        for (int c = 0; c < 4; ++c) { s += accz[r][c] * asrc[c]; t += accz[r][c] * adst[c]; }
        ps[r] = s; pd[r] = t;
    }
    #pragma unroll
    for (int m = 1; m < 16; m <<= 1) {
        #pragma unroll
        for (int r = 0; r < 4; ++r) {
            ps[r] += __shfl_xor(ps[r], m, 64);
            pd[r] += __shfl_xor(pd[r], m, 64);
        }
    }
    if ((tid & 15) == 0) {
        #pragma unroll
        for (int r = 0; r < 4; ++r) {
            int n = row0 + rb + r;
            if (n < N_NODES) { s_src[n] = ps[r]; s_dst[n] = pd[r]; }
        }
    }
    __syncthreads();   // smem reused by next vb / next phase
}

// ============================== phase: partition ==============================
__device__ __forceinline__ void partition_phase(
    int vb, const int* __restrict__ src, const int* __restrict__ dst,
    const float* __restrict__ dfeat, int* __restrict__ gcursor,
    int2* __restrict__ part, Smem& sm)
{
    for (int b = threadIdx.x; b < NBUCKET; b += 256) sm.hist[b] = 0;
    __syncthreads();
    int base = vb * EPB;
    #pragma unroll
    for (int j = 0; j < EPB / 256; ++j) {
        int e = base + j * 256 + threadIdx.x;
        if (e < N_EDGES) atomicAdd(&sm.hist[dst[e] >> NPB_SHIFT], 1);
    }
    __syncthreads();
    for (int b = threadIdx.x; b < NBUCKET; b += 256) {
        int v = sm.hist[b];
        sm.hist[b] = v ? atomicAdd(&gcursor[b], v) : 0;
    }
    __syncthreads();
    #pragma unroll
    for (int j = 0; j < EPB / 256; ++j) {
        int e = base + j * 256 + threadIdx.x;
        if (e < N_EDGES) {
            int d = dst[e];
            int pos = atomicAdd(&sm.hist[d >> NPB_SHIFT], 1);
            part[pos] = make_int2(((d & (NPB - 1)) << 16) | src[e], __float_as_int(dfeat[e]));
        }
    }
    __syncthreads();
}

// ============================== phase: bucket sort ==============================
__device__ __forceinline__ void sort_phase(
    int b, const int2* __restrict__ part, const int* __restrict__ gcursor,
    unsigned* __restrict__ edata, int2* __restrict__ rowse, Smem& sm)
{
    int t = threadIdx.x;
    int beg = b * CAP, end = gcursor[b];
    if (t < NPB) sm.srt.cnt[t] = 0;
    __syncthreads();
    for (int i = beg + t; i < end; i += 256) atomicAdd(&sm.srt.cnt[part[i].x >> 16], 1);
    __syncthreads();
    if (t < NPB) sm.srt.cur[t] = sm.srt.cnt[t];
    __syncthreads();
    for (int off = 1; off < NPB; off <<= 1) {
        int a2 = (t < NPB && t >= off) ? sm.srt.cur[t - off] : 0;
        __syncthreads();
        if (t < NPB) sm.srt.cur[t] += a2;
        __syncthreads();
    }
    if (t < NPB) {
        int n = (b << NPB_SHIFT) + t;
        int cntv = sm.srt.cnt[t];
        int st = beg + sm.srt.cur[t] - cntv;
        if (n < N_NODES) rowse[n] = make_int2(st, st + cntv);
        sm.srt.cur[t] = st;
    }
    __syncthreads();
    for (int i = beg + t; i < end; i += 256) {
        int2 ed = part[i];
        int loc = ed.x >> 16;
        int pos = atomicAdd(&sm.srt.cur[loc], 1);
        edata[pos] = ((unsigned)(ed.x & 0xFFFF) << 16) | (unsigned)f2bf(__int_as_float(ed.y));
    }
    __syncthreads();
}

// ============================== phase: fused GAT ==============================
// GROUP-PER-NODE (16 lanes/node); packed (src<<16|bf16(ex)) single broadcast; 8-deep gather.
template<bool OUT_BF16>
__device__ __forceinline__ void gat_phase(
    int vb, const int2* __restrict__ rowse, const unsigned* __restrict__ edata,
    const float* __restrict__ s_src, const float* __restrict__ s_dst,
    const ushort* __restrict__ zb, const ushort* __restrict__ zib,
    const float* __restrict__ V, const float* __restrict__ A,
    void* __restrict__ out)
{
    const int n = vb * 16 + (threadIdx.x >> 4);
    const int q = threadIdx.x & 15;
    const int gbase = threadIdx.x & 48;

    int2 se = rowse[n];
    int beg = se.x, end = se.y;
    if (beg == end) {
        if (OUT_BF16) {
            ushort4 zz; zz.x = zz.y = zz.z = zz.w = 0;
            ((ushort4*)out)[(size_t)n * 16 + q] = zz;
        } else {
            ((float4*)out)[(size_t)n * 16 + q] = make_float4(0.f, 0.f, 0.f, 0.f);
        }
        return;
    }

    float vae = V[0] * A[2 * DIM];
    float sd = s_dst[n];

    float l = 0.f;
    float4 a0 = make_float4(0.f, 0.f, 0.f, 0.f);
    float4 a1 = make_float4(0.f, 0.f, 0.f, 0.f);

    for (int c0 = beg; c0 < end; c0 += 16) {
        int c = c0 + q;
        bool valid = c < end;
        unsigned w = valid ? edata[c] : 0u;
        int s = (int)(w >> 16);
        float dv = bf2f((ushort)(w & 0xFFFFu));
        float e = s_src[s] + sd + dv * vae;
        e = (e >= 0.f) ? e : 0.01f * e;
        float ex = valid ? __expf(e) : 0.f;

        float cs = ex;
        #pragma unroll
        for (int off = 8; off >= 1; off >>= 1) cs += __shfl_xor(cs, off, 16);
        l += cs;

        unsigned w2 = valid ? (((unsigned)s << 16) | (unsigned)f2bf(ex)) : 0u;

        int cnt = min(16, end - c0);
        for (int k = 0; k < cnt; k += 8) {
            unsigned wsj[8];
            ushort4 v[8];
            #pragma unroll
            for (int j = 0; j < 8; ++j) {
                wsj[j] = __shfl(w2, gbase + k + j, 64);
                v[j] = *(const ushort4*)&zb[((size_t)(wsj[j] >> 16) << 6) + (q << 2)];
            }
            #pragma unroll
            for (int j = 0; j < 8; ++j) {
                float ej = bf2f((ushort)(wsj[j] & 0xFFFFu));
                if (j & 1) {
                    a1.x += ej * bf2f(v[j].x); a1.y += ej * bf2f(v[j].y);
                    a1.z += ej * bf2f(v[j].z); a1.w += ej * bf2f(v[j].w);
                } else {
                    a0.x += ej * bf2f(v[j].x); a0.y += ej * bf2f(v[j].y);
                    a0.z += ej * bf2f(v[j].z); a0.w += ej * bf2f(v[j].w);
                }
            }
        }
    }
    float inv = 1.f / l;
    ushort4 zu = ((const ushort4*)zib)[(size_t)n * 16 + q];
    float4 o;
    o.x = fmaxf(bf2f(zu.x) + (a0.x + a1.x) * inv, 0.f);
    o.y = fmaxf(bf2f(zu.y) + (a0.y + a1.y) * inv, 0.f);
    o.z = fmaxf(bf2f(zu.z) + (a0.z + a1.z) * inv, 0.f);
    o.w = fmaxf(bf2f(zu.w) + (a0.w + a1.w) * inv, 0.f);
    if (OUT_BF16) {
        ushort4 ob;
        ob.x = f2bf(o.x); ob.y = f2bf(o.y); ob.z = f2bf(o.z); ob.w = f2bf(o.w);
        ((ushort4*)out)[(size_t)n * 16 + q] = ob;
    } else {
        ((float4*)out)[(size_t)n * 16 + q] = o;
    }
}

// ============================== mega kernel ==============================
struct GArgs {
    const float *h, *dd;
    const int *src, *dst;
    const float *V0, *W0, *U0, *A0, *V1, *W1, *U1, *A1;
    ushort *zb, *zib, *h1b;
    float *ssrc, *sdst;
    int2 *part;
    unsigned *edata;
    int *gcursor;
    int2 *rowse;
    float *out;
};

__global__ __launch_bounds__(256, 4) void gat_mega(GArgs a)
{
    __shared__ Smem sm;
    cg::grid_group g = cg::this_grid();

    // P0: layer-1 node GEMM; block 0 also seeds slotted cursors
    if (blockIdx.x == 0)
        for (int b = threadIdx.x; b < NBUCKET; b += 256) a.gcursor[b] = b * CAP;
    for (int vb = blockIdx.x; vb < NB_NL; vb += gridDim.x)
        nl_phase<false>(vb, a.h, a.W0, a.U0, a.A0, a.zb, a.zib, a.ssrc, a.sdst, sm);
    g.sync();

    // P1: partition edges into bucket-exclusive slotted ranges
    for (int vb = blockIdx.x; vb < NBLK; vb += gridDim.x)
        partition_phase(vb, a.src, a.dst, a.dd, a.gcursor, a.part, sm);
    g.sync();

    // P2: per-bucket counting sort -> edata + rowse
    for (int vb = blockIdx.x; vb < NBUCKET; vb += gridDim.x)
        sort_phase(vb, a.part, a.gcursor, a.edata, a.rowse, sm);
    g.sync();

    // P3: layer-1 fused GAT -> h1b (bf16)
    for (int vb = blockIdx.x; vb < NB_GAT; vb += gridDim.x)
        gat_phase<true>(vb, a.rowse, a.edata, a.ssrc, a.sdst, a.zb, a.zib, a.V0, a.A0, a.h1b);
    g.sync();

    // P4: layer-2 node GEMM (bf16 input)
    for (int vb = blockIdx.x; vb < NB_NL; vb += gridDim.x)
        nl_phase<true>(vb, a.h1b, a.W1, a.U1, a.A1, a.zb, a.zib, a.ssrc, a.sdst, sm);
    g.sync();

    // P5: layer-2 fused GAT -> out (fp32)
    for (int vb = blockIdx.x; vb < NB_GAT; vb += gridDim.x)
        gat_phase<false>(vb, a.rowse, a.edata, a.ssrc, a.sdst, a.zb, a.zib, a.V1, a.A1, a.out);
}

// ============================== driver ==============================
extern "C" void kernel_launch(void* const* d_in, const int* in_sizes, int n_in,
                              void* d_out, int out_size, void* d_ws, size_t ws_size,
                              hipStream_t stream)
{
    const size_t ND = (size_t)N_NODES * DIM;   // 3.2M

    GArgs a;
    a.h  = (const float*)d_in[0];
    a.dd = (const float*)d_in[1];
    a.src = (const int*)d_in[2];
    a.dst = (const int*)d_in[3];
    a.V0 = (const float*)d_in[4];
    a.W0 = (const float*)d_in[5];
    a.U0 = (const float*)d_in[6];
    a.A0 = (const float*)d_in[7];
    a.V1 = (const float*)d_in[8];
    a.W1 = (const float*)d_in[9];
    a.U1 = (const float*)d_in[10];
    a.A1 = (const float*)d_in[11];

    float* ws = (float*)d_ws;
    a.zb   = (ushort*)ws;                    // ND ushort
    a.zib  = a.zb + ND;                      // ND ushort
    a.h1b  = a.zib + ND;                     // ND ushort
    a.ssrc = ws + (3 * ND) / 2;              // N floats
    a.sdst = a.ssrc + N_NODES;               // N floats
    a.rowse = (int2*)(a.sdst + N_NODES);     // N int2 (8B-aligned offset)
    a.part  = a.rowse + N_NODES;             // NBUCKET*CAP int2
    a.edata = (unsigned*)(a.part + (size_t)NBUCKET * CAP);  // NBUCKET*CAP u32
    a.gcursor = (int*)(a.edata + (size_t)NBUCKET * CAP);    // NBUCKET int
    a.out = (float*)d_out;

    int maxb = 0;
    if (hipOccupancyMaxActiveBlocksPerMultiprocessor(&maxb, (const void*)gat_mega, 256, 0) != hipSuccess || maxb < 1)
        maxb = 1;
    int grid = 256 * maxb;                   // 256 CUs on MI355X
    if (grid > 2048) grid = 2048;

    void* kp[] = { (void*)&a };
    hipLaunchCooperativeKernel((const void*)gat_mega, dim3(grid), dim3(256), kp, 0, stream);
}

// Round 10
// 195.329 us; speedup vs baseline: 2.8210x; 2.8210x over previous
//
#include <hip/hip_runtime.h>
#include <math.h>

#define N_NODES 50000
#define N_EDGES 800000
#define DIM 64
#define NPB 128
#define NPB_SHIFT 7
#define NBUCKET 391          // ceil(50000/128)
#define CAP 2560             // slot capacity per bucket (mean 2046, sd ~45 -> 11 sigma)
#define EPB 2048             // edges per partition vblock
#define NBLK 391             // ceil(800000/2048)
#define NB_NL 782            // ceil(50000/64)
#define NB_GAT 3125          // 50000/16

// ---- bf16 helpers (RNE) ----
__device__ __forceinline__ ushort f2bf(float x) {
    unsigned b = __float_as_uint(x);
    return (ushort)((b + 0x7FFFu + ((b >> 16) & 1u)) >> 16);
}
__device__ __forceinline__ float bf2f(ushort u) {
    return __uint_as_float(((unsigned)u) << 16);
}

// ============================== node GEMM body ==============================
// zb = bf16(h @ W^T), zib = bf16(h @ U^T), s_src/s_dst = attention projections of z.
template<bool IN_BF16>
__device__ __forceinline__ void nl_body(
    int vb, const void* __restrict__ hin, const float* __restrict__ W,
    const float* __restrict__ U, const float* __restrict__ A,
    ushort* __restrict__ zb, ushort* __restrict__ zib,
    float* __restrict__ s_src, float* __restrict__ s_dst,
    float (*Ws)[DIM + 1], float (*Us)[DIM + 1], float (*hs)[DIM + 1])
{
    const int tid = threadIdx.x;
    const int row0 = vb * 64;

    for (int i = tid; i < 1024; i += 256) {
        int r = i >> 4, c = (i & 15) * 4;
        float4 w4 = ((const float4*)W)[i];
        float4 u4 = ((const float4*)U)[i];
        Ws[r][c] = w4.x; Ws[r][c + 1] = w4.y; Ws[r][c + 2] = w4.z; Ws[r][c + 3] = w4.w;
        Us[r][c] = u4.x; Us[r][c + 1] = u4.y; Us[r][c + 2] = u4.z; Us[r][c + 3] = u4.w;
        int n = row0 + r;
        float4 h4 = make_float4(0.f, 0.f, 0.f, 0.f);
        if (n < N_NODES) {
            if (IN_BF16) {
                ushort4 hb = ((const ushort4*)hin)[((size_t)n * DIM + c) >> 2];
                h4 = make_float4(bf2f(hb.x), bf2f(hb.y), bf2f(hb.z), bf2f(hb.w));
            } else {
                h4 = ((const float4*)hin)[((size_t)n * DIM + c) >> 2];
            }
        }
        hs[r][c] = h4.x; hs[r][c + 1] = h4.y; hs[r][c + 2] = h4.z; hs[r][c + 3] = h4.w;
    }
    __syncthreads();

    const int rb = (tid >> 4) * 4;
    const int cb = (tid & 15) * 4;

    float accz[4][4] = {{0}}, accu[4][4] = {{0}};
    #pragma unroll 8
    for (int k = 0; k < DIM; ++k) {
        float hv[4], wv[4], uv[4];
        #pragma unroll
        for (int r = 0; r < 4; ++r) hv[r] = hs[rb + r][k];
        #pragma unroll
        for (int c = 0; c < 4; ++c) { wv[c] = Ws[cb + c][k]; uv[c] = Us[cb + c][k]; }
        #pragma unroll
        for (int r = 0; r < 4; ++r)
            #pragma unroll
            for (int c = 0; c < 4; ++c) {
                accz[r][c] += hv[r] * wv[c];
                accu[r][c] += hv[r] * uv[c];
            }
    }

    float asrc[4], adst[4];
    #pragma unroll
    for (int c = 0; c < 4; ++c) { asrc[c] = A[cb + c]; adst[c] = A[DIM + cb + c]; }

    float ps[4], pd[4];
    #pragma unroll
    for (int r = 0; r < 4; ++r) {
        int n = row0 + rb + r;
        if (n < N_NODES) {
            ushort4 vz, vu;
            vz.x = f2bf(accz[r][0]); vz.y = f2bf(accz[r][1]);
            vz.z = f2bf(accz[r][2]); vz.w = f2bf(accz[r][3]);
            vu.x = f2bf(accu[r][0]); vu.y = f2bf(accu[r][1]);
            vu.z = f2bf(accu[r][2]); vu.w = f2bf(accu[r][3]);
            *(ushort4*)&zb[(size_t)n * DIM + cb]  = vz;
            *(ushort4*)&zib[(size_t)n * DIM + cb] = vu;
        }
        float s = 0.f, t = 0.f;
        #pragma unroll
        for (int c = 0; c < 4; ++c) { s += accz[r][c] * asrc[c]; t += accz[r][c] * adst[c]; }
        ps[r] = s; pd[r] = t;
    }
    #pragma unroll
    for (int m = 1; m < 16; m <<= 1) {
        #pragma unroll
        for (int r = 0; r < 4; ++r) {
            ps[r] += __shfl_xor(ps[r], m, 64);
            pd[r] += __shfl_xor(pd[r], m, 64);
        }
    }
    if ((tid & 15) == 0) {
        #pragma unroll
        for (int r = 0; r < 4; ++r) {
            int n = row0 + rb + r;
            if (n < N_NODES) { s_src[n] = ps[r]; s_dst[n] = pd[r]; }
        }
    }
}

// ============================== partition body ==============================
// Slotted: bucket b owns part[b*CAP .. b*CAP+CAP); gcursor[b] (zero-seeded) counts fill.
__device__ __forceinline__ void partition_body(
    int vb, const int* __restrict__ src, const int* __restrict__ dst,
    const float* __restrict__ dfeat, int* __restrict__ gcursor,
    int2* __restrict__ part, int* __restrict__ h)
{
    for (int b = threadIdx.x; b < NBUCKET; b += 256) h[b] = 0;
    __syncthreads();
    int base = vb * EPB;
    #pragma unroll
    for (int j = 0; j < EPB / 256; ++j) {
        int e = base + j * 256 + threadIdx.x;
        if (e < N_EDGES) atomicAdd(&h[dst[e] >> NPB_SHIFT], 1);
    }
    __syncthreads();
    // reserve: h[b] becomes this block's bucket-local write cursor
    for (int b = threadIdx.x; b < NBUCKET; b += 256) {
        int v = h[b];
        h[b] = v ? atomicAdd(&gcursor[b], v) : 0;
    }
    __syncthreads();
    #pragma unroll
    for (int j = 0; j < EPB / 256; ++j) {
        int e = base + j * 256 + threadIdx.x;
        if (e < N_EDGES) {
            int d = dst[e];
            int b = d >> NPB_SHIFT;
            int pos = b * CAP + atomicAdd(&h[b], 1);
            part[pos] = make_int2(((d & (NPB - 1)) << 16) | src[e], __float_as_int(dfeat[e]));
        }
    }
}

// ============================== K1: nl1 (2/3 of blocks) || partition (1/3) ==============================
struct K1NL { float Ws[DIM][DIM + 1]; float Us[DIM][DIM + 1]; float hs[64][DIM + 1]; };
union K1U { K1NL nl; int hist[NBUCKET]; };

__global__ __launch_bounds__(256) void k1_nl_part(
    const float* __restrict__ h, const float* __restrict__ W0,
    const float* __restrict__ U0, const float* __restrict__ A0,
    ushort* __restrict__ zb, ushort* __restrict__ zib,
    float* __restrict__ ssrc, float* __restrict__ sdst,
    const int* __restrict__ src, const int* __restrict__ dst,
    const float* __restrict__ dd, int* __restrict__ gcursor, int2* __restrict__ part)
{
    __shared__ K1U sm;
    int bid = blockIdx.x;               // 1173 = 3*391 blocks
    int m = bid % 3;
    if (m == 2)
        partition_body(bid / 3, src, dst, dd, gcursor, part, sm.hist);
    else
        nl_body<false>((bid / 3) * 2 + m, h, W0, U0, A0, zb, zib, ssrc, sdst,
                       sm.nl.Ws, sm.nl.Us, sm.nl.hs);
}

// standalone layer-2 GEMM
__global__ __launch_bounds__(256) void node_linear2(
    const ushort* __restrict__ h1b, const float* __restrict__ W,
    const float* __restrict__ U, const float* __restrict__ A,
    ushort* __restrict__ zb, ushort* __restrict__ zib,
    float* __restrict__ ssrc, float* __restrict__ sdst)
{
    __shared__ K1NL sm;
    nl_body<true>(blockIdx.x, h1b, W, U, A, zb, zib, ssrc, sdst, sm.Ws, sm.Us, sm.hs);
}

// ============================== bucket sort ==============================
// one block per bucket: counting sort by local dst; emit edata=(src<<16)|bf16(dval), rowse
__global__ __launch_bounds__(256) void bucket_sort(
    const int2* __restrict__ part, const int* __restrict__ gcursor,
    unsigned* __restrict__ edata, int2* __restrict__ rowse)
{
    __shared__ int cnt[NPB];
    __shared__ int cur[NPB];
    int b = blockIdx.x, t = threadIdx.x;
    int beg = b * CAP, end = beg + gcursor[b];
    if (t < NPB) cnt[t] = 0;
    __syncthreads();
    for (int i = beg + t; i < end; i += 256) atomicAdd(&cnt[part[i].x >> 16], 1);
    __syncthreads();
    if (t < NPB) cur[t] = cnt[t];
    __syncthreads();
    for (int off = 1; off < NPB; off <<= 1) {
        int a = (t < NPB && t >= off) ? cur[t - off] : 0;
        __syncthreads();
        if (t < NPB) cur[t] += a;
        __syncthreads();
    }
    if (t < NPB) {
        int n = (b << NPB_SHIFT) + t;
        int cv = cnt[t];
        int st = beg + cur[t] - cv;
        if (n < N_NODES) rowse[n] = make_int2(st, st + cv);
        cur[t] = st;
    }
    __syncthreads();
    for (int i = beg + t; i < end; i += 256) {
        int2 ed = part[i];
        int loc = ed.x >> 16;
        int pos = atomicAdd(&cur[loc], 1);
        edata[pos] = ((unsigned)(ed.x & 0xFFFF) << 16) | (unsigned)f2bf(__int_as_float(ed.y));
    }
}

// ============================== fused GAT ==============================
// GROUP-PER-NODE (16 lanes/node); packed (src<<16|bf16(ex)) single broadcast; 8-deep gather.
template<bool OUT_BF16>
__global__ __launch_bounds__(256) void gat_fused(
    const int2* __restrict__ rowse, const unsigned* __restrict__ edata,
    const float* __restrict__ s_src, const float* __restrict__ s_dst,
    const ushort* __restrict__ zb, const ushort* __restrict__ zib,
    const float* __restrict__ V, const float* __restrict__ A,
    void* __restrict__ out)
{
    const int n = blockIdx.x * 16 + (threadIdx.x >> 4);   // 50000 = 16*3125, no tail
    const int q = threadIdx.x & 15;
    const int gbase = threadIdx.x & 48;

    int2 se = rowse[n];
    int beg = se.x, end = se.y;
    if (beg == end) {
        if (OUT_BF16) {
            ushort4 zz; zz.x = zz.y = zz.z = zz.w = 0;
            ((ushort4*)out)[(size_t)n * 16 + q] = zz;
        } else {
            ((float4*)out)[(size_t)n * 16 + q] = make_float4(0.f, 0.f, 0.f, 0.f);
        }
        return;
    }

    float vae = V[0] * A[2 * DIM];
    float sd = s_dst[n];

    float l = 0.f;
    float4 a0 = make_float4(0.f, 0.f, 0.f, 0.f);
    float4 a1 = make_float4(0.f, 0.f, 0.f, 0.f);

    for (int c0 = beg; c0 < end; c0 += 16) {
        int c = c0 + q;
        bool valid = c < end;
        unsigned w = valid ? edata[c] : 0u;
        int s = (int)(w >> 16);
        float dv = bf2f((ushort)(w & 0xFFFFu));
        float e = s_src[s] + sd + dv * vae;
        e = (e >= 0.f) ? e : 0.01f * e;
        float ex = valid ? __expf(e) : 0.f;

        float cs = ex;
        #pragma unroll
        for (int off = 8; off >= 1; off >>= 1) cs += __shfl_xor(cs, off, 16);
        l += cs;

        unsigned w2 = valid ? (((unsigned)s << 16) | (unsigned)f2bf(ex)) : 0u;

        int cnt = min(16, end - c0);
        for (int k = 0; k < cnt; k += 8) {
            unsigned wsj[8];
            ushort4 v[8];
            #pragma unroll
            for (int j = 0; j < 8; ++j) {
                wsj[j] = __shfl(w2, gbase + k + j, 64);
                v[j] = *(const ushort4*)&zb[((size_t)(wsj[j] >> 16) << 6) + (q << 2)];
            }
            #pragma unroll
            for (int j = 0; j < 8; ++j) {
                float ej = bf2f((ushort)(wsj[j] & 0xFFFFu));
                if (j & 1) {
                    a1.x += ej * bf2f(v[j].x); a1.y += ej * bf2f(v[j].y);
                    a1.z += ej * bf2f(v[j].z); a1.w += ej * bf2f(v[j].w);
                } else {
                    a0.x += ej * bf2f(v[j].x); a0.y += ej * bf2f(v[j].y);
                    a0.z += ej * bf2f(v[j].z); a0.w += ej * bf2f(v[j].w);
                }
            }
        }
    }
    float inv = 1.f / l;
    ushort4 zu = ((const ushort4*)zib)[(size_t)n * 16 + q];
    float4 o;
    o.x = fmaxf(bf2f(zu.x) + (a0.x + a1.x) * inv, 0.f);
    o.y = fmaxf(bf2f(zu.y) + (a0.y + a1.y) * inv, 0.f);
    o.z = fmaxf(bf2f(zu.z) + (a0.z + a1.z) * inv, 0.f);
    o.w = fmaxf(bf2f(zu.w) + (a0.w + a1.w) * inv, 0.f);
    if (OUT_BF16) {
        ushort4 ob;
        ob.x = f2bf(o.x); ob.y = f2bf(o.y); ob.z = f2bf(o.z); ob.w = f2bf(o.w);
        ((ushort4*)out)[(size_t)n * 16 + q] = ob;
    } else {
        ((float4*)out)[(size_t)n * 16 + q] = o;
    }
}

// ============================== driver ==============================
extern "C" void kernel_launch(void* const* d_in, const int* in_sizes, int n_in,
                              void* d_out, int out_size, void* d_ws, size_t ws_size,
                              hipStream_t stream)
{
    const float* h  = (const float*)d_in[0];
    const float* dd = (const float*)d_in[1];
    const int* src  = (const int*)d_in[2];
    const int* dst  = (const int*)d_in[3];
    const float* V0 = (const float*)d_in[4];
    const float* W0 = (const float*)d_in[5];
    const float* U0 = (const float*)d_in[6];
    const float* A0 = (const float*)d_in[7];
    const float* V1 = (const float*)d_in[8];
    const float* W1 = (const float*)d_in[9];
    const float* U1 = (const float*)d_in[10];
    const float* A1 = (const float*)d_in[11];

    const size_t ND = (size_t)N_NODES * DIM;   // 3.2M
    float* ws    = (float*)d_ws;
    ushort* zb   = (ushort*)ws;                     // ND ushort
    ushort* zib  = zb + ND;                         // ND ushort
    ushort* h1b  = zib + ND;                        // ND ushort
    float* ssrc  = ws + (3 * ND) / 2;               // N floats
    float* sdst  = ssrc + N_NODES;                  // N floats
    int2*  rowse = (int2*)(sdst + N_NODES);         // N int2 (8B-aligned offset)
    int2*  part  = rowse + N_NODES;                 // NBUCKET*CAP int2 (8 MB)
    unsigned* edata = (unsigned*)(part + (size_t)NBUCKET * CAP);  // NBUCKET*CAP u32
    int*   gcursor  = (int*)(edata + (size_t)NBUCKET * CAP);      // NBUCKET int
    float* out   = (float*)d_out;

    // zero bucket cursors (1.6 KB), then layer-1 GEMM || edge partition in ONE launch
    hipMemsetAsync(gcursor, 0, NBUCKET * sizeof(int), stream);
    k1_nl_part<<<3 * NBLK, 256, 0, stream>>>(h, W0, U0, A0, zb, zib, ssrc, sdst,
                                             src, dst, dd, gcursor, part);
    bucket_sort<<<NBUCKET, 256, 0, stream>>>(part, gcursor, edata, rowse);
    gat_fused<true><<<NB_GAT, 256, 0, stream>>>(rowse, edata, ssrc, sdst, zb, zib, V0, A0, h1b);
    node_linear2<<<NB_NL, 256, 0, stream>>>(h1b, W1, U1, A1, zb, zib, ssrc, sdst);
    gat_fused<false><<<NB_GAT, 256, 0, stream>>>(rowse, edata, ssrc, sdst, zb, zib, V1, A1, out);
}